// Round 1
// baseline (2314.781 us; speedup 1.0000x reference)
//
#include <hip/hip_runtime.h>
#include <math.h>

#define S_LEN 2048
#define DMODEL 1024
#define NH 8
#define DK_ 128
#define DV_ 128
#define KD_ 1024
#define KCONV 4

// ---------------- GEMM: C[M,N] = A[M,K] @ B[N,K]^T (fp32) ----------------
__global__ __launch_bounds__(256) void gemm_abt(
    const float* __restrict__ A, const float* __restrict__ B,
    float* __restrict__ C, int M, int N, int Kd) {
  __shared__ float As[16][68];  // pad 68: 16B-aligned rows, 2-way write conflict (free)
  __shared__ float Bs[16][68];
  const int tid = threadIdx.x;
  const int m0 = blockIdx.y * 64, n0 = blockIdx.x * 64;
  const int tx = tid & 15, ty = tid >> 4;
  const int lk = tid & 15, lr = tid >> 4;
  float acc[4][4] = {};
  for (int k0 = 0; k0 < Kd; k0 += 16) {
#pragma unroll
    for (int i = 0; i < 4; i++) {
      int m = m0 + lr + 16 * i;
      As[lk][lr + 16 * i] = (m < M) ? A[(size_t)m * Kd + k0 + lk] : 0.f;
      int n = n0 + lr + 16 * i;
      Bs[lk][lr + 16 * i] = (n < N) ? B[(size_t)n * Kd + k0 + lk] : 0.f;
    }
    __syncthreads();
#pragma unroll
    for (int kk = 0; kk < 16; kk++) {
      float4 a4 = *(const float4*)&As[kk][ty * 4];
      float4 b4 = *(const float4*)&Bs[kk][tx * 4];
      float av[4] = {a4.x, a4.y, a4.z, a4.w};
      float bv[4] = {b4.x, b4.y, b4.z, b4.w};
#pragma unroll
      for (int i = 0; i < 4; i++)
#pragma unroll
        for (int j = 0; j < 4; j++) acc[i][j] = fmaf(av[i], bv[j], acc[i][j]);
    }
    __syncthreads();
  }
#pragma unroll
  for (int i = 0; i < 4; i++) {
    int m = m0 + ty * 4 + i;
    if (m >= M) continue;
#pragma unroll
    for (int j = 0; j < 4; j++) {
      int n = n0 + tx * 4 + j;
      if (n < N) C[(size_t)m * N + n] = acc[i][j];
    }
  }
}

// -------- depthwise causal conv(K=4) + silu for q,k,v and ve; mix v ----------
__global__ __launch_bounds__(256) void conv_silu_mix(
    const float* __restrict__ qp, const float* __restrict__ kp,
    const float* __restrict__ vp, const float* __restrict__ vep,
    const float* __restrict__ wq, const float* __restrict__ wk,
    const float* __restrict__ wv, const float* __restrict__ lam,
    float* __restrict__ qc, float* __restrict__ kc, float* __restrict__ vmx) {
  int idx = blockIdx.x * 256 + threadIdx.x;
  if (idx >= S_LEN * KD_) return;
  int s = idx >> 10, d = idx & 1023;
  float aq = 0.f, ak = 0.f, av = 0.f, ae = 0.f;
#pragma unroll
  for (int i = 0; i < KCONV; i++) {
    int ss = s - (KCONV - 1) + i;
    if (ss < 0) continue;
    size_t off = (size_t)ss * KD_ + d;
    aq = fmaf(qp[off], wq[d * KCONV + i], aq);
    ak = fmaf(kp[off], wk[d * KCONV + i], ak);
    av = fmaf(vp[off], wv[d * KCONV + i], av);
    ae = fmaf(vep[off], wv[d * KCONV + i], ae);
  }
  qc[idx] = aq / (1.f + expf(-aq));
  kc[idx] = ak / (1.f + expf(-ak));
  float sv = av / (1.f + expf(-av));
  float se = ae / (1.f + expf(-ae));
  vmx[idx] = lam[0] * sv + lam[1] * se;
}

// ------ eg = exp(-exp(A_log)*softplus(graw+dt_bias)); gate = sigmoid(graw2+bg2);
// ------ beta = sigmoid(bpre)   (all in place) ------
__global__ __launch_bounds__(256) void eg_beta_gate(
    float* __restrict__ graw, float* __restrict__ graw2, float* __restrict__ bpre,
    const float* __restrict__ dt_bias, const float* __restrict__ A_log,
    const float* __restrict__ bg2) {
  int idx = blockIdx.x * 256 + threadIdx.x;
  if (idx < S_LEN * KD_) {
    int c = idx & 1023;
    float xv = graw[idx] + dt_bias[c];
    float sp = (xv > 20.f) ? xv : log1pf(expf(xv));
    float g = -expf(A_log[c >> 7]) * sp;
    graw[idx] = expf(g);
    float gv = graw2[idx] + bg2[c];
    graw2[idx] = 1.f / (1.f + expf(-gv));
  }
  if (idx < S_LEN * NH) bpre[idx] = 1.f / (1.f + expf(-bpre[idx]));
}

// ---------------- l2norm (q gets *DK^-0.5), in place; one wave per (s,h) ------
__global__ __launch_bounds__(64) void l2norm_qk(float* __restrict__ q, float* __restrict__ k) {
  size_t base = (size_t)blockIdx.x * DK_;
  int t = threadIdx.x;
  float q0 = q[base + t], q1 = q[base + t + 64];
  float k0 = k[base + t], k1 = k[base + t + 64];
  float sq = q0 * q0 + q1 * q1;
  float sk = k0 * k0 + k1 * k1;
#pragma unroll
  for (int off = 32; off > 0; off >>= 1) {
    sq += __shfl_xor(sq, off);
    sk += __shfl_xor(sk, off);
  }
  float rq = rsqrtf(sq + 1e-6f) * 0.08838834764831845f;  // DK^-0.5
  float rk = rsqrtf(sk + 1e-6f);
  q[base + t] = q0 * rq; q[base + t + 64] = q1 * rq;
  k[base + t] = k0 * rk; k[base + t + 64] = k1 * rk;
}

// ---------------- KDA recurrent scan, column-split ----------------
// block = (h, vg): 16 state columns; wave handles 4 columns; lane = kg(16) x vsub(4)
// each lane holds S[8k x 1v]; dot reductions are in-wave shfl_xor butterflies.
__global__ __launch_bounds__(256) void kda_scan(
    const float* __restrict__ qn, const float* __restrict__ kn,
    const float* __restrict__ vm, const float* __restrict__ eg,
    const float* __restrict__ beta, float* __restrict__ o) {
  const int h = blockIdx.x >> 3;
  const int vg = blockIdx.x & 7;
  const int wave = threadIdx.x >> 6;
  const int lane = threadIdx.x & 63;
  const int kg = lane >> 2;
  const int vsub = lane & 3;
  const int v = vg * 16 + wave * 4 + vsub;
  const float* kb = kn + h * DK_ + kg * 8;
  const float* qb = qn + h * DK_ + kg * 8;
  const float* eb = eg + h * DK_ + kg * 8;
  const float* vb = vm + h * DV_ + v;
  float S0 = 0, S1 = 0, S2 = 0, S3 = 0, S4 = 0, S5 = 0, S6 = 0, S7 = 0;
  float4 kA = *(const float4*)kb, kB = *(const float4*)(kb + 4);
  float4 qA = *(const float4*)qb, qB = *(const float4*)(qb + 4);
  float4 eA = *(const float4*)eb, eB = *(const float4*)(eb + 4);
  float vt = vb[0];
  float bt = beta[h];
  for (int s = 0; s < S_LEN; s++) {
    float4 nkA, nkB, nqA, nqB, neA, neB;
    float nvt = 0.f, nbt = 0.f;
    if (s + 1 < S_LEN) {  // prefetch next step while computing current
      size_t off = (size_t)(s + 1) * KD_;
      nkA = *(const float4*)(kb + off); nkB = *(const float4*)(kb + off + 4);
      nqA = *(const float4*)(qb + off); nqB = *(const float4*)(qb + off + 4);
      neA = *(const float4*)(eb + off); neB = *(const float4*)(eb + off + 4);
      nvt = vb[off];
      nbt = beta[(size_t)(s + 1) * NH + h];
    } else {
      nkA = kA; nkB = kB; nqA = qA; nqB = qB; neA = eA; neB = eB;
    }
    // decay
    S0 *= eA.x; S1 *= eA.y; S2 *= eA.z; S3 *= eA.w;
    S4 *= eB.x; S5 *= eB.y; S6 *= eB.z; S7 *= eB.w;
    // k . S (per column)
    float kd = kA.x * S0 + kA.y * S1 + kA.z * S2 + kA.w * S3 +
               kB.x * S4 + kB.y * S5 + kB.z * S6 + kB.w * S7;
    kd += __shfl_xor(kd, 4);
    kd += __shfl_xor(kd, 8);
    kd += __shfl_xor(kd, 16);
    kd += __shfl_xor(kd, 32);
    float vnw = (vt - kd) * bt;
    // S += k (x) v_new ; q . S
    S0 = fmaf(kA.x, vnw, S0); S1 = fmaf(kA.y, vnw, S1);
    S2 = fmaf(kA.z, vnw, S2); S3 = fmaf(kA.w, vnw, S3);
    S4 = fmaf(kB.x, vnw, S4); S5 = fmaf(kB.y, vnw, S5);
    S6 = fmaf(kB.z, vnw, S6); S7 = fmaf(kB.w, vnw, S7);
    float qd = qA.x * S0 + qA.y * S1 + qA.z * S2 + qA.w * S3 +
               qB.x * S4 + qB.y * S5 + qB.z * S6 + qB.w * S7;
    qd += __shfl_xor(qd, 4);
    qd += __shfl_xor(qd, 8);
    qd += __shfl_xor(qd, 16);
    qd += __shfl_xor(qd, 32);
    if (kg == 0) o[(size_t)s * KD_ + h * DK_ + v] = qd;
    kA = nkA; kB = nkB; qA = nqA; qB = nqB; eA = neA; eB = neB;
    vt = nvt; bt = nbt;
  }
}

// --------- FusedRMSNormGated (sigmoid gate precomputed), in place ----------
__global__ __launch_bounds__(64) void gated_rmsnorm(
    float* __restrict__ o, const float* __restrict__ gate, const float* __restrict__ wn) {
  size_t base = (size_t)blockIdx.x * DV_;
  int t = threadIdx.x;
  float a = o[base + t], b = o[base + t + 64];
  float ss = a * a + b * b;
#pragma unroll
  for (int off = 32; off > 0; off >>= 1) ss += __shfl_xor(ss, off);
  float r = rsqrtf(ss * (1.f / 128.f) + 1e-5f);
  o[base + t] = a * r * wn[t] * gate[base + t];
  o[base + t + 64] = b * r * wn[t + 64] * gate[base + t + 64];
}

extern "C" void kernel_launch(void* const* d_in, const int* in_sizes, int n_in,
                              void* d_out, int out_size, void* d_ws, size_t ws_size,
                              hipStream_t stream) {
  const float* x = (const float*)d_in[0];
  const float* ve = (const float*)d_in[1];
  const float* lam = (const float*)d_in[2];
  const float* Wq = (const float*)d_in[3];
  const float* Wk = (const float*)d_in[4];
  const float* Wv = (const float*)d_in[5];
  const float* Wo = (const float*)d_in[6];
  const float* wq_conv = (const float*)d_in[7];
  const float* wk_conv = (const float*)d_in[8];
  const float* wv_conv = (const float*)d_in[9];
  const float* Wf1 = (const float*)d_in[10];
  const float* Wf2 = (const float*)d_in[11];
  const float* Wb = (const float*)d_in[12];
  const float* A_log = (const float*)d_in[13];
  const float* dt_bias = (const float*)d_in[14];
  const float* Wg1 = (const float*)d_in[15];
  const float* Wg2 = (const float*)d_in[16];
  const float* bg2 = (const float*)d_in[17];
  const float* w_norm = (const float*)d_in[18];
  float* out = (float*)d_out;

  float* ws = (float*)d_ws;
  const size_t SZ = (size_t)S_LEN * KD_;  // 2M floats
  float* q_pre = ws;            // [S,KD]
  float* k_pre = ws + SZ;
  float* v_pre = ws + 2 * SZ;
  float* ve_pre = ws + 3 * SZ;
  float* q_c = ws + 4 * SZ;     // becomes qn in place
  float* k_c = ws + 5 * SZ;     // becomes kn in place
  float* v_mix = ws + 6 * SZ;
  // after conv consumes the *_pre buffers, reuse them:
  float* f1 = ve_pre;                              // [S,128]
  float* g1 = ve_pre + (size_t)S_LEN * DV_;        // [S,128]
  float* bpre = ve_pre + 2 * (size_t)S_LEN * DV_;  // [S,8] -> beta
  float* graw = q_pre;    // -> eg in place
  float* graw2 = k_pre;   // -> gate in place
  float* o_buf = v_pre;   // -> gated o in place
  // total ws use: 7 * 2M floats = 56 MB

  dim3 blk(256);
  dim3 g_big(16, 32);  // N=1024, M=2048
  dim3 g_128(2, 32);   // N=128
  dim3 g_8(1, 32);     // N=8
  int ew_blocks = (S_LEN * KD_ + 255) / 256;

  gemm_abt<<<g_big, blk, 0, stream>>>(x, Wq, q_pre, S_LEN, KD_, DMODEL);
  gemm_abt<<<g_big, blk, 0, stream>>>(x, Wk, k_pre, S_LEN, KD_, DMODEL);
  gemm_abt<<<g_big, blk, 0, stream>>>(x, Wv, v_pre, S_LEN, KD_, DMODEL);
  gemm_abt<<<g_big, blk, 0, stream>>>(ve, Wv, ve_pre, S_LEN, KD_, DMODEL);

  conv_silu_mix<<<ew_blocks, blk, 0, stream>>>(q_pre, k_pre, v_pre, ve_pre,
                                               wq_conv, wk_conv, wv_conv, lam,
                                               q_c, k_c, v_mix);

  gemm_abt<<<g_128, blk, 0, stream>>>(x, Wf1, f1, S_LEN, DV_, DMODEL);
  gemm_abt<<<g_128, blk, 0, stream>>>(x, Wg1, g1, S_LEN, DV_, DMODEL);
  gemm_abt<<<g_8, blk, 0, stream>>>(x, Wb, bpre, S_LEN, NH, DMODEL);

  gemm_abt<<<g_big, blk, 0, stream>>>(f1, Wf2, graw, S_LEN, KD_, DV_);
  gemm_abt<<<g_big, blk, 0, stream>>>(g1, Wg2, graw2, S_LEN, KD_, DV_);

  eg_beta_gate<<<ew_blocks, blk, 0, stream>>>(graw, graw2, bpre, dt_bias, A_log, bg2);

  l2norm_qk<<<dim3(S_LEN * NH), dim3(64), 0, stream>>>(q_c, k_c);

  kda_scan<<<dim3(64), blk, 0, stream>>>(q_c, k_c, v_mix, graw, bpre, o_buf);

  gated_rmsnorm<<<dim3(S_LEN * NH), dim3(64), 0, stream>>>(o_buf, graw2, w_norm);

  gemm_abt<<<g_big, blk, 0, stream>>>(o_buf, Wo, out, S_LEN, DMODEL, KD_);
}

// Round 2
// 1539.823 us; speedup vs baseline: 1.5033x; 1.5033x over previous
//
#include <hip/hip_runtime.h>
#include <math.h>

#define S_LEN 2048
#define DMODEL 1024
#define NH 8
#define DK_ 128
#define DV_ 128
#define KD_ 1024
#define KCONV 4
#define WSTEPS 16

// ---------------- GEMM: C[M,N] = A[M,K] @ B[N,K]^T (fp32) ----------------
__global__ __launch_bounds__(256) void gemm_abt(
    const float* __restrict__ A, const float* __restrict__ B,
    float* __restrict__ C, int M, int N, int Kd) {
  __shared__ float As[16][68];
  __shared__ float Bs[16][68];
  const int tid = threadIdx.x;
  const int m0 = blockIdx.y * 64, n0 = blockIdx.x * 64;
  const int tx = tid & 15, ty = tid >> 4;
  const int lk = tid & 15, lr = tid >> 4;
  float acc[4][4] = {};
  for (int k0 = 0; k0 < Kd; k0 += 16) {
#pragma unroll
    for (int i = 0; i < 4; i++) {
      int m = m0 + lr + 16 * i;
      As[lk][lr + 16 * i] = (m < M) ? A[(size_t)m * Kd + k0 + lk] : 0.f;
      int n = n0 + lr + 16 * i;
      Bs[lk][lr + 16 * i] = (n < N) ? B[(size_t)n * Kd + k0 + lk] : 0.f;
    }
    __syncthreads();
#pragma unroll
    for (int kk = 0; kk < 16; kk++) {
      float4 a4 = *(const float4*)&As[kk][ty * 4];
      float4 b4 = *(const float4*)&Bs[kk][tx * 4];
      float av[4] = {a4.x, a4.y, a4.z, a4.w};
      float bv[4] = {b4.x, b4.y, b4.z, b4.w};
#pragma unroll
      for (int i = 0; i < 4; i++)
#pragma unroll
        for (int j = 0; j < 4; j++) acc[i][j] = fmaf(av[i], bv[j], acc[i][j]);
    }
    __syncthreads();
  }
#pragma unroll
  for (int i = 0; i < 4; i++) {
    int m = m0 + ty * 4 + i;
    if (m >= M) continue;
#pragma unroll
    for (int j = 0; j < 4; j++) {
      int n = n0 + tx * 4 + j;
      if (n < N) C[(size_t)m * N + n] = acc[i][j];
    }
  }
}

// -------- depthwise causal conv(K=4) + silu for q,k,v and ve; mix v ----------
__global__ __launch_bounds__(256) void conv_silu_mix(
    const float* __restrict__ qp, const float* __restrict__ kp,
    const float* __restrict__ vp, const float* __restrict__ vep,
    const float* __restrict__ wq, const float* __restrict__ wk,
    const float* __restrict__ wv, const float* __restrict__ lam,
    float* __restrict__ qc, float* __restrict__ kc, float* __restrict__ vmx) {
  int idx = blockIdx.x * 256 + threadIdx.x;
  if (idx >= S_LEN * KD_) return;
  int s = idx >> 10, d = idx & 1023;
  float aq = 0.f, ak = 0.f, av = 0.f, ae = 0.f;
#pragma unroll
  for (int i = 0; i < KCONV; i++) {
    int ss = s - (KCONV - 1) + i;
    if (ss < 0) continue;
    size_t off = (size_t)ss * KD_ + d;
    aq = fmaf(qp[off], wq[d * KCONV + i], aq);
    ak = fmaf(kp[off], wk[d * KCONV + i], ak);
    av = fmaf(vp[off], wv[d * KCONV + i], av);
    ae = fmaf(vep[off], wv[d * KCONV + i], ae);
  }
  qc[idx] = aq / (1.f + expf(-aq));
  kc[idx] = ak / (1.f + expf(-ak));
  float sv = av / (1.f + expf(-av));
  float se = ae / (1.f + expf(-ae));
  vmx[idx] = lam[0] * sv + lam[1] * se;
}

// ------ eg = exp(-exp(A_log)*softplus(graw+dt_bias)); gate = sigmoid(graw2+bg2);
// ------ beta = sigmoid(bpre)   (all in place) ------
__global__ __launch_bounds__(256) void eg_beta_gate(
    float* __restrict__ graw, float* __restrict__ graw2, float* __restrict__ bpre,
    const float* __restrict__ dt_bias, const float* __restrict__ A_log,
    const float* __restrict__ bg2) {
  int idx = blockIdx.x * 256 + threadIdx.x;
  if (idx < S_LEN * KD_) {
    int c = idx & 1023;
    float xv = graw[idx] + dt_bias[c];
    float sp = (xv > 20.f) ? xv : log1pf(expf(xv));
    float g = -expf(A_log[c >> 7]) * sp;
    graw[idx] = expf(g);
    float gv = graw2[idx] + bg2[c];
    graw2[idx] = 1.f / (1.f + expf(-gv));
  }
  if (idx < S_LEN * NH) bpre[idx] = 1.f / (1.f + expf(-bpre[idx]));
}

// ---------------- l2norm (q gets *DK^-0.5), in place; one wave per (s,h) ------
__global__ __launch_bounds__(64) void l2norm_qk(float* __restrict__ q, float* __restrict__ k) {
  size_t base = (size_t)blockIdx.x * DK_;
  int t = threadIdx.x;
  float q0 = q[base + t], q1 = q[base + t + 64];
  float k0 = k[base + t], k1 = k[base + t + 64];
  float sq = q0 * q0 + q1 * q1;
  float sk = k0 * k0 + k1 * k1;
#pragma unroll
  for (int off = 32; off > 0; off >>= 1) {
    sq += __shfl_xor(sq, off);
    sk += __shfl_xor(sk, off);
  }
  float rq = rsqrtf(sq + 1e-6f) * 0.08838834764831845f;  // DK^-0.5
  float rk = rsqrtf(sk + 1e-6f);
  q[base + t] = q0 * rq; q[base + t + 64] = q1 * rq;
  k[base + t] = k0 * rk; k[base + t + 64] = k1 * rk;
}

// ---- 16-lane (DPP-row) butterfly sum: quad xor1, xor2, half-mirror, mirror ----
__device__ __forceinline__ float row16_sum(float x) {
  int v = __float_as_int(x);
  x += __int_as_float(__builtin_amdgcn_update_dpp(0, v, 0xB1, 0xF, 0xF, true));
  v = __float_as_int(x);
  x += __int_as_float(__builtin_amdgcn_update_dpp(0, v, 0x4E, 0xF, 0xF, true));
  v = __float_as_int(x);
  x += __int_as_float(__builtin_amdgcn_update_dpp(0, v, 0x141, 0xF, 0xF, true));
  v = __float_as_int(x);
  x += __int_as_float(__builtin_amdgcn_update_dpp(0, v, 0x140, 0xF, 0xF, true));
  return x;
}

// ---------------- KDA recurrent scan, LDS-windowed, DPP reductions ------------
// block = (h, vg): 16 state columns. lane: kg = lane&15 (8 k-elems each),
// vsub = (lane>>4)&3, wave = tid>>6; column = vg*16 + wave*4 + vsub.
// k/q/e/v/beta staged in LDS windows of 16 steps, double-buffered; next
// window's global loads issued before the 16-step compute to hide HBM latency.
__global__ __launch_bounds__(256) void kda_scan(
    const float* __restrict__ qn, const float* __restrict__ kn,
    const float* __restrict__ vm, const float* __restrict__ eg,
    const float* __restrict__ beta, float* __restrict__ o) {
  __shared__ float kbuf[2][WSTEPS][128];
  __shared__ float qbuf[2][WSTEPS][128];
  __shared__ float ebuf[2][WSTEPS][128];
  __shared__ float vbuf[2][WSTEPS][16];
  __shared__ float bbuf[2][WSTEPS];
  const int h = blockIdx.x >> 3;
  const int vg = blockIdx.x & 7;
  const int tid = threadIdx.x;
  const int kg = tid & 15;
  const int vsub = (tid >> 4) & 3;
  const int wave = tid >> 6;
  const int colw = wave * 4 + vsub;  // 0..15
  // fill-thread mapping: 256 threads cover 16 steps x 128 cols (8 floats each)
  const int fi = tid >> 4;
  const int fj = (tid & 15) * 8;

  float4 r0, r1, r2, r3, r4, r5;
  float rv, rb;
  // ---- window 0: load + commit ----
  {
    size_t off = (size_t)fi * KD_ + h * DK_ + fj;
    r0 = *(const float4*)(kn + off); r1 = *(const float4*)(kn + off + 4);
    r2 = *(const float4*)(qn + off); r3 = *(const float4*)(qn + off + 4);
    r4 = *(const float4*)(eg + off); r5 = *(const float4*)(eg + off + 4);
    rv = vm[(size_t)fi * KD_ + h * DV_ + vg * 16 + (tid & 15)];
    rb = (tid < WSTEPS) ? beta[(size_t)tid * NH + h] : 0.f;
    *(float4*)&kbuf[0][fi][fj] = r0; *(float4*)&kbuf[0][fi][fj + 4] = r1;
    *(float4*)&qbuf[0][fi][fj] = r2; *(float4*)&qbuf[0][fi][fj + 4] = r3;
    *(float4*)&ebuf[0][fi][fj] = r4; *(float4*)&ebuf[0][fi][fj + 4] = r5;
    vbuf[0][fi][tid & 15] = rv;
    if (tid < WSTEPS) bbuf[0][tid] = rb;
  }
  __syncthreads();

  float S0 = 0, S1 = 0, S2 = 0, S3 = 0, S4 = 0, S5 = 0, S6 = 0, S7 = 0;
  // prefetch step 0 of buffer 0
  float4 kA = *(float4*)&kbuf[0][0][kg * 8], kB = *(float4*)&kbuf[0][0][kg * 8 + 4];
  float4 qA = *(float4*)&qbuf[0][0][kg * 8], qB = *(float4*)&qbuf[0][0][kg * 8 + 4];
  float4 eA = *(float4*)&ebuf[0][0][kg * 8], eB = *(float4*)&ebuf[0][0][kg * 8 + 4];
  float vt = vbuf[0][0][colw];
  float bt = bbuf[0][0];

  const int NW = S_LEN / WSTEPS;  // 128
  for (int w = 0; w < NW; w++) {
    const int cur = w & 1, nxt = cur ^ 1;
    const bool more = (w + 1 < NW);
    if (more) {  // issue next window's global loads now; consume after compute
      size_t s0 = (size_t)(w + 1) * WSTEPS;
      size_t off = (s0 + fi) * KD_ + h * DK_ + fj;
      r0 = *(const float4*)(kn + off); r1 = *(const float4*)(kn + off + 4);
      r2 = *(const float4*)(qn + off); r3 = *(const float4*)(qn + off + 4);
      r4 = *(const float4*)(eg + off); r5 = *(const float4*)(eg + off + 4);
      rv = vm[(s0 + fi) * KD_ + h * DV_ + vg * 16 + (tid & 15)];
      rb = (tid < WSTEPS) ? beta[(s0 + tid) * NH + h] : 0.f;
    }
#pragma unroll
    for (int s = 0; s < WSTEPS; s++) {
      float4 nkA, nkB, nqA, nqB, neA, neB;
      float nvt = 0.f, nbt = 0.f;
      if (s + 1 < WSTEPS) {  // LDS prefetch of next step (compile-time branch)
        nkA = *(float4*)&kbuf[cur][s + 1][kg * 8];
        nkB = *(float4*)&kbuf[cur][s + 1][kg * 8 + 4];
        nqA = *(float4*)&qbuf[cur][s + 1][kg * 8];
        nqB = *(float4*)&qbuf[cur][s + 1][kg * 8 + 4];
        neA = *(float4*)&ebuf[cur][s + 1][kg * 8];
        neB = *(float4*)&ebuf[cur][s + 1][kg * 8 + 4];
        nvt = vbuf[cur][s + 1][colw];
        nbt = bbuf[cur][s + 1];
      }
      // decay
      S0 *= eA.x; S1 *= eA.y; S2 *= eA.z; S3 *= eA.w;
      S4 *= eB.x; S5 *= eB.y; S6 *= eB.z; S7 *= eB.w;
      // kd = k . S[:,col]  (two ILP chains, then 4-stage DPP butterfly)
      float kd0 = fmaf(kA.y, S1, kA.x * S0);
      kd0 = fmaf(kA.z, S2, kd0);
      kd0 = fmaf(kA.w, S3, kd0);
      float kd1 = fmaf(kB.y, S5, kB.x * S4);
      kd1 = fmaf(kB.z, S6, kd1);
      kd1 = fmaf(kB.w, S7, kd1);
      float kd = row16_sum(kd0 + kd1);
      float vnw = (vt - kd) * bt;
      // state update
      S0 = fmaf(kA.x, vnw, S0); S1 = fmaf(kA.y, vnw, S1);
      S2 = fmaf(kA.z, vnw, S2); S3 = fmaf(kA.w, vnw, S3);
      S4 = fmaf(kB.x, vnw, S4); S5 = fmaf(kB.y, vnw, S5);
      S6 = fmaf(kB.z, vnw, S6); S7 = fmaf(kB.w, vnw, S7);
      // output
      float qd0 = fmaf(qA.y, S1, qA.x * S0);
      qd0 = fmaf(qA.z, S2, qd0);
      qd0 = fmaf(qA.w, S3, qd0);
      float qd1 = fmaf(qB.y, S5, qB.x * S4);
      qd1 = fmaf(qB.z, S6, qd1);
      qd1 = fmaf(qB.w, S7, qd1);
      float qd = row16_sum(qd0 + qd1);
      if (kg == 0)
        o[(size_t)(w * WSTEPS + s) * KD_ + h * DK_ + vg * 16 + colw] = qd;
      if (s + 1 < WSTEPS) {
        kA = nkA; kB = nkB; qA = nqA; qB = nqB; eA = neA; eB = neB;
        vt = nvt; bt = nbt;
      }
    }
    if (more) {  // commit next window to LDS (loads have had ~2000 cyc)
      *(float4*)&kbuf[nxt][fi][fj] = r0; *(float4*)&kbuf[nxt][fi][fj + 4] = r1;
      *(float4*)&qbuf[nxt][fi][fj] = r2; *(float4*)&qbuf[nxt][fi][fj + 4] = r3;
      *(float4*)&ebuf[nxt][fi][fj] = r4; *(float4*)&ebuf[nxt][fi][fj + 4] = r5;
      vbuf[nxt][fi][tid & 15] = rv;
      if (tid < WSTEPS) bbuf[nxt][tid] = rb;
    }
    __syncthreads();
    if (more) {  // prefetch step 0 of the new window
      kA = *(float4*)&kbuf[nxt][0][kg * 8]; kB = *(float4*)&kbuf[nxt][0][kg * 8 + 4];
      qA = *(float4*)&qbuf[nxt][0][kg * 8]; qB = *(float4*)&qbuf[nxt][0][kg * 8 + 4];
      eA = *(float4*)&ebuf[nxt][0][kg * 8]; eB = *(float4*)&ebuf[nxt][0][kg * 8 + 4];
      vt = vbuf[nxt][0][colw];
      bt = bbuf[nxt][0];
    }
  }
}

// --------- FusedRMSNormGated (sigmoid gate precomputed), in place ----------
__global__ __launch_bounds__(64) void gated_rmsnorm(
    float* __restrict__ o, const float* __restrict__ gate, const float* __restrict__ wn) {
  size_t base = (size_t)blockIdx.x * DV_;
  int t = threadIdx.x;
  float a = o[base + t], b = o[base + t + 64];
  float ss = a * a + b * b;
#pragma unroll
  for (int off = 32; off > 0; off >>= 1) ss += __shfl_xor(ss, off);
  float r = rsqrtf(ss * (1.f / 128.f) + 1e-5f);
  o[base + t] = a * r * wn[t] * gate[base + t];
  o[base + t + 64] = b * r * wn[t + 64] * gate[base + t + 64];
}

extern "C" void kernel_launch(void* const* d_in, const int* in_sizes, int n_in,
                              void* d_out, int out_size, void* d_ws, size_t ws_size,
                              hipStream_t stream) {
  const float* x = (const float*)d_in[0];
  const float* ve = (const float*)d_in[1];
  const float* lam = (const float*)d_in[2];
  const float* Wq = (const float*)d_in[3];
  const float* Wk = (const float*)d_in[4];
  const float* Wv = (const float*)d_in[5];
  const float* Wo = (const float*)d_in[6];
  const float* wq_conv = (const float*)d_in[7];
  const float* wk_conv = (const float*)d_in[8];
  const float* wv_conv = (const float*)d_in[9];
  const float* Wf1 = (const float*)d_in[10];
  const float* Wf2 = (const float*)d_in[11];
  const float* Wb = (const float*)d_in[12];
  const float* A_log = (const float*)d_in[13];
  const float* dt_bias = (const float*)d_in[14];
  const float* Wg1 = (const float*)d_in[15];
  const float* Wg2 = (const float*)d_in[16];
  const float* bg2 = (const float*)d_in[17];
  const float* w_norm = (const float*)d_in[18];
  float* out = (float*)d_out;

  float* ws = (float*)d_ws;
  const size_t SZ = (size_t)S_LEN * KD_;  // 2M floats
  float* q_pre = ws;
  float* k_pre = ws + SZ;
  float* v_pre = ws + 2 * SZ;
  float* ve_pre = ws + 3 * SZ;
  float* q_c = ws + 4 * SZ;
  float* k_c = ws + 5 * SZ;
  float* v_mix = ws + 6 * SZ;
  float* f1 = ve_pre;
  float* g1 = ve_pre + (size_t)S_LEN * DV_;
  float* bpre = ve_pre + 2 * (size_t)S_LEN * DV_;
  float* graw = q_pre;
  float* graw2 = k_pre;
  float* o_buf = v_pre;

  dim3 blk(256);
  dim3 g_big(16, 32);
  dim3 g_128(2, 32);
  dim3 g_8(1, 32);
  int ew_blocks = (S_LEN * KD_ + 255) / 256;

  gemm_abt<<<g_big, blk, 0, stream>>>(x, Wq, q_pre, S_LEN, KD_, DMODEL);
  gemm_abt<<<g_big, blk, 0, stream>>>(x, Wk, k_pre, S_LEN, KD_, DMODEL);
  gemm_abt<<<g_big, blk, 0, stream>>>(x, Wv, v_pre, S_LEN, KD_, DMODEL);
  gemm_abt<<<g_big, blk, 0, stream>>>(ve, Wv, ve_pre, S_LEN, KD_, DMODEL);

  conv_silu_mix<<<ew_blocks, blk, 0, stream>>>(q_pre, k_pre, v_pre, ve_pre,
                                               wq_conv, wk_conv, wv_conv, lam,
                                               q_c, k_c, v_mix);

  gemm_abt<<<g_128, blk, 0, stream>>>(x, Wf1, f1, S_LEN, DV_, DMODEL);
  gemm_abt<<<g_128, blk, 0, stream>>>(x, Wg1, g1, S_LEN, DV_, DMODEL);
  gemm_abt<<<g_8, blk, 0, stream>>>(x, Wb, bpre, S_LEN, NH, DMODEL);

  gemm_abt<<<g_big, blk, 0, stream>>>(f1, Wf2, graw, S_LEN, KD_, DV_);
  gemm_abt<<<g_big, blk, 0, stream>>>(g1, Wg2, graw2, S_LEN, KD_, DV_);

  eg_beta_gate<<<ew_blocks, blk, 0, stream>>>(graw, graw2, bpre, dt_bias, A_log, bg2);

  l2norm_qk<<<dim3(S_LEN * NH), dim3(64), 0, stream>>>(q_c, k_c);

  kda_scan<<<dim3(64), blk, 0, stream>>>(q_c, k_c, v_mix, graw, bpre, o_buf);

  gated_rmsnorm<<<dim3(S_LEN * NH), dim3(64), 0, stream>>>(o_buf, graw2, w_norm);

  gemm_abt<<<g_big, blk, 0, stream>>>(o_buf, Wo, out, S_LEN, DMODEL, KD_);
}

// Round 3
// 852.403 us; speedup vs baseline: 2.7156x; 1.8064x over previous
//
#include <hip/hip_runtime.h>
#include <math.h>
#include <stdint.h>

#define S_LEN 2048
#define DMODEL 1024
#define NH 8
#define DK_ 128
#define DV_ 128
#define KD_ 1024
#define KCONV 4
#define WSTEPS 16

typedef short bf16x8 __attribute__((ext_vector_type(8)));   // 8 bf16 in 4 VGPRs
typedef float f32x4 __attribute__((ext_vector_type(4)));

__device__ __forceinline__ uint16_t f2bf(float f) {  // RNE
  uint32_t u = __float_as_uint(f);
  u += 0x7FFF + ((u >> 16) & 1);
  return (uint16_t)(u >> 16);
}

__device__ __forceinline__ void glds16(const uint16_t* g, uint16_t* l) {
  __builtin_amdgcn_global_load_lds(
      (const __attribute__((address_space(1))) void*)g,
      (__attribute__((address_space(3))) void*)l, 16, 0, 0);
}

// ---------------- fused fp32 -> bf16 cast for up to 8 tensors ----------------
struct CastArgs {
  const float* s[8];
  uint16_t* d[8];
  int n[8];
};
__global__ __launch_bounds__(256) void cast_multi(CastArgs a) {
  int i = blockIdx.y;
  int base = (blockIdx.x * 256 + threadIdx.x) * 8;
  if (base >= a.n[i]) return;
  const float4* sp = (const float4*)(a.s[i] + base);
  float4 x0 = sp[0], x1 = sp[1];
  uint32_t p0 = (uint32_t)f2bf(x0.x) | ((uint32_t)f2bf(x0.y) << 16);
  uint32_t p1 = (uint32_t)f2bf(x0.z) | ((uint32_t)f2bf(x0.w) << 16);
  uint32_t p2 = (uint32_t)f2bf(x1.x) | ((uint32_t)f2bf(x1.y) << 16);
  uint32_t p3 = (uint32_t)f2bf(x1.z) | ((uint32_t)f2bf(x1.w) << 16);
  uint4 v = {p0, p1, p2, p3};
  *(uint4*)(a.d[i] + base) = v;
}

// ---------------- bf16 MFMA GEMM: C[M,N] = A[M,K] @ B[N,K]^T ----------------
// 128x128 tile, BK=32, 4 waves (2x2 of 64x64), 16x16x32 MFMA, global_load_lds,
// XOR chunk swizzle (cc ^ ((row>>2)&3)) so frag ds_read_b128 is 2-way only.
struct GJobs {
  const uint16_t* A[4];
  const uint16_t* B[4];
  void* C[4];
};
template <bool OUT_BF16>
__global__ __launch_bounds__(256) void gemm_mfma(GJobs j, int N, int K) {
  __shared__ uint16_t Asb[128 * 32];
  __shared__ uint16_t Bsb[128 * 32];
  const uint16_t* __restrict__ A = j.A[blockIdx.z];
  const uint16_t* __restrict__ B = j.B[blockIdx.z];
  const int tid = threadIdx.x;
  const int w = tid >> 6, lane = tid & 63;
  const int m0 = blockIdx.y * 128, n0 = blockIdx.x * 128;
  const int mw = (w & 1) * 64, nw = (w >> 1) * 64;
  // staging: chunk c covers (row = c>>2, phys cc = c&3); global chunk is
  // cc ^ ((row>>2)&3)  (XOR swizzle baked in by loading swizzled source)
  const int c0 = tid, c1 = 256 + tid;
  const int r0 = c0 >> 2, cl0 = (c0 & 3) ^ ((r0 >> 2) & 3);
  const int r1 = c1 >> 2, cl1 = (c1 & 3) ^ ((r1 >> 2) & 3);
  const uint16_t* gA0 = A + (size_t)(m0 + r0) * K + cl0 * 8;
  const uint16_t* gA1 = A + (size_t)(m0 + r1) * K + cl1 * 8;
  const uint16_t* gB0 = B + (size_t)(n0 + r0) * K + cl0 * 8;
  const uint16_t* gB1 = B + (size_t)(n0 + r1) * K + cl1 * 8;
  uint16_t* lA0 = Asb + w * 512;
  uint16_t* lA1 = Asb + 2048 + w * 512;
  uint16_t* lB0 = Bsb + w * 512;
  uint16_t* lB1 = Bsb + 2048 + w * 512;

  const int l15 = lane & 15, q = lane >> 4;
  const int ccq = q ^ ((l15 >> 2) & 3);  // physical chunk for fragment reads

  f32x4 acc[4][4] = {};
  for (int k0 = 0; k0 < K; k0 += 32) {
    glds16(gA0 + k0, lA0);
    glds16(gA1 + k0, lA1);
    glds16(gB0 + k0, lB0);
    glds16(gB1 + k0, lB1);
    __syncthreads();
    bf16x8 af[4], bfr[4];
#pragma unroll
    for (int i = 0; i < 4; i++)
      af[i] = *(const bf16x8*)&Asb[(mw + i * 16 + l15) * 32 + ccq * 8];
#pragma unroll
    for (int jx = 0; jx < 4; jx++)
      bfr[jx] = *(const bf16x8*)&Bsb[(nw + jx * 16 + l15) * 32 + ccq * 8];
#pragma unroll
    for (int i = 0; i < 4; i++)
#pragma unroll
      for (int jx = 0; jx < 4; jx++)
        acc[i][jx] = __builtin_amdgcn_mfma_f32_16x16x32_bf16(af[i], bfr[jx],
                                                             acc[i][jx], 0, 0, 0);
    __syncthreads();
  }
  // C/D layout: col = lane&15 (n), row = (lane>>4)*4 + reg (m)
#pragma unroll
  for (int i = 0; i < 4; i++) {
#pragma unroll
    for (int jx = 0; jx < 4; jx++) {
      int n = n0 + nw + jx * 16 + l15;
#pragma unroll
      for (int r = 0; r < 4; r++) {
        int m = m0 + mw + i * 16 + q * 4 + r;
        if (OUT_BF16)
          ((uint16_t*)j.C[blockIdx.z])[(size_t)m * N + n] = f2bf(acc[i][jx][r]);
        else
          ((float*)j.C[blockIdx.z])[(size_t)m * N + n] = acc[i][jx][r];
      }
    }
  }
}

// ---------------- fp32 GEMM (kept for numerically-sensitive g-path + Wb) -----
__global__ __launch_bounds__(256) void gemm_abt(
    const float* __restrict__ A, const float* __restrict__ B,
    float* __restrict__ C, int M, int N, int Kd) {
  __shared__ float As[16][68];
  __shared__ float Bs[16][68];
  const int tid = threadIdx.x;
  const int m0 = blockIdx.y * 64, n0 = blockIdx.x * 64;
  const int tx = tid & 15, ty = tid >> 4;
  const int lk = tid & 15, lr = tid >> 4;
  float acc[4][4] = {};
  for (int k0 = 0; k0 < Kd; k0 += 16) {
#pragma unroll
    for (int i = 0; i < 4; i++) {
      int m = m0 + lr + 16 * i;
      As[lk][lr + 16 * i] = (m < M) ? A[(size_t)m * Kd + k0 + lk] : 0.f;
      int n = n0 + lr + 16 * i;
      Bs[lk][lr + 16 * i] = (n < N) ? B[(size_t)n * Kd + k0 + lk] : 0.f;
    }
    __syncthreads();
#pragma unroll
    for (int kk = 0; kk < 16; kk++) {
      float4 a4 = *(const float4*)&As[kk][ty * 4];
      float4 b4 = *(const float4*)&Bs[kk][tx * 4];
      float av[4] = {a4.x, a4.y, a4.z, a4.w};
      float bv[4] = {b4.x, b4.y, b4.z, b4.w};
#pragma unroll
      for (int i = 0; i < 4; i++)
#pragma unroll
        for (int jx = 0; jx < 4; jx++) acc[i][jx] = fmaf(av[i], bv[jx], acc[i][jx]);
    }
    __syncthreads();
  }
#pragma unroll
  for (int i = 0; i < 4; i++) {
    int m = m0 + ty * 4 + i;
    if (m >= M) continue;
#pragma unroll
    for (int jx = 0; jx < 4; jx++) {
      int n = n0 + tx * 4 + jx;
      if (n < N) C[(size_t)m * N + n] = acc[i][jx];
    }
  }
}

// -------- depthwise causal conv(K=4) + silu for q,k,v and ve; mix v ----------
__global__ __launch_bounds__(256) void conv_silu_mix(
    const float* __restrict__ qp, const float* __restrict__ kp,
    const float* __restrict__ vp, const float* __restrict__ vep,
    const float* __restrict__ wq, const float* __restrict__ wk,
    const float* __restrict__ wv, const float* __restrict__ lam,
    float* __restrict__ qc, float* __restrict__ kc, float* __restrict__ vmx) {
  int idx = blockIdx.x * 256 + threadIdx.x;
  if (idx >= S_LEN * KD_) return;
  int s = idx >> 10, d = idx & 1023;
  float aq = 0.f, ak = 0.f, av = 0.f, ae = 0.f;
#pragma unroll
  for (int i = 0; i < KCONV; i++) {
    int ss = s - (KCONV - 1) + i;
    if (ss < 0) continue;
    size_t off = (size_t)ss * KD_ + d;
    aq = fmaf(qp[off], wq[d * KCONV + i], aq);
    ak = fmaf(kp[off], wk[d * KCONV + i], ak);
    av = fmaf(vp[off], wv[d * KCONV + i], av);
    ae = fmaf(vep[off], wv[d * KCONV + i], ae);
  }
  qc[idx] = aq / (1.f + expf(-aq));
  kc[idx] = ak / (1.f + expf(-ak));
  float sv = av / (1.f + expf(-av));
  float se = ae / (1.f + expf(-ae));
  vmx[idx] = lam[0] * sv + lam[1] * se;
}

__global__ __launch_bounds__(256) void eg_beta_gate(
    float* __restrict__ graw, float* __restrict__ graw2, float* __restrict__ bpre,
    const float* __restrict__ dt_bias, const float* __restrict__ A_log,
    const float* __restrict__ bg2) {
  int idx = blockIdx.x * 256 + threadIdx.x;
  if (idx < S_LEN * KD_) {
    int c = idx & 1023;
    float xv = graw[idx] + dt_bias[c];
    float sp = (xv > 20.f) ? xv : log1pf(expf(xv));
    float g = -expf(A_log[c >> 7]) * sp;
    graw[idx] = expf(g);
    float gv = graw2[idx] + bg2[c];
    graw2[idx] = 1.f / (1.f + expf(-gv));
  }
  if (idx < S_LEN * NH) bpre[idx] = 1.f / (1.f + expf(-bpre[idx]));
}

__global__ __launch_bounds__(64) void l2norm_qk(float* __restrict__ q, float* __restrict__ k) {
  size_t base = (size_t)blockIdx.x * DK_;
  int t = threadIdx.x;
  float q0 = q[base + t], q1 = q[base + t + 64];
  float k0 = k[base + t], k1 = k[base + t + 64];
  float sq = q0 * q0 + q1 * q1;
  float sk = k0 * k0 + k1 * k1;
#pragma unroll
  for (int off = 32; off > 0; off >>= 1) {
    sq += __shfl_xor(sq, off);
    sk += __shfl_xor(sk, off);
  }
  float rq = rsqrtf(sq + 1e-6f) * 0.08838834764831845f;
  float rk = rsqrtf(sk + 1e-6f);
  q[base + t] = q0 * rq; q[base + t + 64] = q1 * rq;
  k[base + t] = k0 * rk; k[base + t + 64] = k1 * rk;
}

__device__ __forceinline__ float row16_sum(float x) {
  int v = __float_as_int(x);
  x += __int_as_float(__builtin_amdgcn_update_dpp(0, v, 0xB1, 0xF, 0xF, true));
  v = __float_as_int(x);
  x += __int_as_float(__builtin_amdgcn_update_dpp(0, v, 0x4E, 0xF, 0xF, true));
  v = __float_as_int(x);
  x += __int_as_float(__builtin_amdgcn_update_dpp(0, v, 0x141, 0xF, 0xF, true));
  v = __float_as_int(x);
  x += __int_as_float(__builtin_amdgcn_update_dpp(0, v, 0x140, 0xF, 0xF, true));
  return x;
}

// swizzled column offset for 8-float group of k-group kg: 2-way banks only
#define SWK(kg) ((kg) * 8 + ((kg) >> 2) * 4)
#define ROWF 148

// ---------------- KDA recurrent scan, LDS-windowed, DPP reductions ------------
__global__ __launch_bounds__(256) void kda_scan(
    const float* __restrict__ qn, const float* __restrict__ kn,
    const float* __restrict__ vm, const float* __restrict__ eg,
    const float* __restrict__ beta, float* __restrict__ o) {
  __shared__ float kbuf[2][WSTEPS][ROWF];
  __shared__ float qbuf[2][WSTEPS][ROWF];
  __shared__ float ebuf[2][WSTEPS][ROWF];
  __shared__ float vbuf[2][WSTEPS][16];
  __shared__ float bbuf[2][WSTEPS];
  const int h = blockIdx.x >> 3;
  const int vg = blockIdx.x & 7;
  const int tid = threadIdx.x;
  const int kg = tid & 15;
  const int vsub = (tid >> 4) & 3;
  const int wave = tid >> 6;
  const int colw = wave * 4 + vsub;
  const int fi = tid >> 4;
  const int fkg = tid & 15;          // writer k-group
  const int fj = fkg * 8;            // global col base
  const int fjs = SWK(fkg);          // swizzled LDS col base
  const int swr = SWK(kg);           // reader swizzled base

  float4 r0, r1, r2, r3, r4, r5;
  float rv, rb;
  {
    size_t off = (size_t)fi * KD_ + h * DK_ + fj;
    r0 = *(const float4*)(kn + off); r1 = *(const float4*)(kn + off + 4);
    r2 = *(const float4*)(qn + off); r3 = *(const float4*)(qn + off + 4);
    r4 = *(const float4*)(eg + off); r5 = *(const float4*)(eg + off + 4);
    rv = vm[(size_t)fi * KD_ + h * DV_ + vg * 16 + fkg];
    rb = (tid < WSTEPS) ? beta[(size_t)tid * NH + h] : 0.f;
    *(float4*)&kbuf[0][fi][fjs] = r0; *(float4*)&kbuf[0][fi][fjs + 4] = r1;
    *(float4*)&qbuf[0][fi][fjs] = r2; *(float4*)&qbuf[0][fi][fjs + 4] = r3;
    *(float4*)&ebuf[0][fi][fjs] = r4; *(float4*)&ebuf[0][fi][fjs + 4] = r5;
    vbuf[0][fi][fkg] = rv;
    if (tid < WSTEPS) bbuf[0][tid] = rb;
  }
  __syncthreads();

  float S0 = 0, S1 = 0, S2 = 0, S3 = 0, S4 = 0, S5 = 0, S6 = 0, S7 = 0;
  float4 kA = *(float4*)&kbuf[0][0][swr], kB = *(float4*)&kbuf[0][0][swr + 4];
  float4 qA = *(float4*)&qbuf[0][0][swr], qB = *(float4*)&qbuf[0][0][swr + 4];
  float4 eA = *(float4*)&ebuf[0][0][swr], eB = *(float4*)&ebuf[0][0][swr + 4];
  float vt = vbuf[0][0][colw];
  float bt = bbuf[0][0];

  const int NW = S_LEN / WSTEPS;
  for (int w = 0; w < NW; w++) {
    const int cur = w & 1, nxt = cur ^ 1;
    const bool more = (w + 1 < NW);
    if (more) {
      size_t s0 = (size_t)(w + 1) * WSTEPS;
      size_t off = (s0 + fi) * KD_ + h * DK_ + fj;
      r0 = *(const float4*)(kn + off); r1 = *(const float4*)(kn + off + 4);
      r2 = *(const float4*)(qn + off); r3 = *(const float4*)(qn + off + 4);
      r4 = *(const float4*)(eg + off); r5 = *(const float4*)(eg + off + 4);
      rv = vm[(s0 + fi) * KD_ + h * DV_ + vg * 16 + fkg];
      rb = (tid < WSTEPS) ? beta[(s0 + tid) * NH + h] : 0.f;
    }
#pragma unroll
    for (int s = 0; s < WSTEPS; s++) {
      float4 nkA, nkB, nqA, nqB, neA, neB;
      float nvt = 0.f, nbt = 0.f;
      if (s + 1 < WSTEPS) {
        nkA = *(float4*)&kbuf[cur][s + 1][swr];
        nkB = *(float4*)&kbuf[cur][s + 1][swr + 4];
        nqA = *(float4*)&qbuf[cur][s + 1][swr];
        nqB = *(float4*)&qbuf[cur][s + 1][swr + 4];
        neA = *(float4*)&ebuf[cur][s + 1][swr];
        neB = *(float4*)&ebuf[cur][s + 1][swr + 4];
        nvt = vbuf[cur][s + 1][colw];
        nbt = bbuf[cur][s + 1];
      }
      S0 *= eA.x; S1 *= eA.y; S2 *= eA.z; S3 *= eA.w;
      S4 *= eB.x; S5 *= eB.y; S6 *= eB.z; S7 *= eB.w;
      float kd0 = fmaf(kA.y, S1, kA.x * S0);
      kd0 = fmaf(kA.z, S2, kd0);
      kd0 = fmaf(kA.w, S3, kd0);
      float kd1 = fmaf(kB.y, S5, kB.x * S4);
      kd1 = fmaf(kB.z, S6, kd1);
      kd1 = fmaf(kB.w, S7, kd1);
      float kd = row16_sum(kd0 + kd1);
      float vnw = (vt - kd) * bt;
      S0 = fmaf(kA.x, vnw, S0); S1 = fmaf(kA.y, vnw, S1);
      S2 = fmaf(kA.z, vnw, S2); S3 = fmaf(kA.w, vnw, S3);
      S4 = fmaf(kB.x, vnw, S4); S5 = fmaf(kB.y, vnw, S5);
      S6 = fmaf(kB.z, vnw, S6); S7 = fmaf(kB.w, vnw, S7);
      float qd0 = fmaf(qA.y, S1, qA.x * S0);
      qd0 = fmaf(qA.z, S2, qd0);
      qd0 = fmaf(qA.w, S3, qd0);
      float qd1 = fmaf(qB.y, S5, qB.x * S4);
      qd1 = fmaf(qB.z, S6, qd1);
      qd1 = fmaf(qB.w, S7, qd1);
      float qd = row16_sum(qd0 + qd1);
      if (kg == 0)
        o[(size_t)(w * WSTEPS + s) * KD_ + h * DK_ + vg * 16 + colw] = qd;
      if (s + 1 < WSTEPS) {
        kA = nkA; kB = nkB; qA = nqA; qB = nqB; eA = neA; eB = neB;
        vt = nvt; bt = nbt;
      }
    }
    if (more) {
      *(float4*)&kbuf[nxt][fi][fjs] = r0; *(float4*)&kbuf[nxt][fi][fjs + 4] = r1;
      *(float4*)&qbuf[nxt][fi][fjs] = r2; *(float4*)&qbuf[nxt][fi][fjs + 4] = r3;
      *(float4*)&ebuf[nxt][fi][fjs] = r4; *(float4*)&ebuf[nxt][fi][fjs + 4] = r5;
      vbuf[nxt][fi][fkg] = rv;
      if (tid < WSTEPS) bbuf[nxt][tid] = rb;
    }
    __syncthreads();
    if (more) {
      kA = *(float4*)&kbuf[nxt][0][swr]; kB = *(float4*)&kbuf[nxt][0][swr + 4];
      qA = *(float4*)&qbuf[nxt][0][swr]; qB = *(float4*)&qbuf[nxt][0][swr + 4];
      eA = *(float4*)&ebuf[nxt][0][swr]; eB = *(float4*)&ebuf[nxt][0][swr + 4];
      vt = vbuf[nxt][0][colw];
      bt = bbuf[nxt][0];
    }
  }
}

// ---- FusedRMSNormGated: writes bf16 output (feeds Wo MFMA GEMM) ----
__global__ __launch_bounds__(64) void gated_rmsnorm(
    const float* __restrict__ o, const float* __restrict__ gate,
    const float* __restrict__ wn, uint16_t* __restrict__ ob) {
  size_t base = (size_t)blockIdx.x * DV_;
  int t = threadIdx.x;
  float a = o[base + t], b = o[base + t + 64];
  float ss = a * a + b * b;
#pragma unroll
  for (int off = 32; off > 0; off >>= 1) ss += __shfl_xor(ss, off);
  float r = rsqrtf(ss * (1.f / 128.f) + 1e-5f);
  ob[base + t] = f2bf(a * r * wn[t] * gate[base + t]);
  ob[base + t + 64] = f2bf(b * r * wn[t + 64] * gate[base + t + 64]);
}

extern "C" void kernel_launch(void* const* d_in, const int* in_sizes, int n_in,
                              void* d_out, int out_size, void* d_ws, size_t ws_size,
                              hipStream_t stream) {
  const float* x = (const float*)d_in[0];
  const float* ve = (const float*)d_in[1];
  const float* lam = (const float*)d_in[2];
  const float* Wq = (const float*)d_in[3];
  const float* Wk = (const float*)d_in[4];
  const float* Wv = (const float*)d_in[5];
  const float* Wo = (const float*)d_in[6];
  const float* wq_conv = (const float*)d_in[7];
  const float* wk_conv = (const float*)d_in[8];
  const float* wv_conv = (const float*)d_in[9];
  const float* Wf1 = (const float*)d_in[10];
  const float* Wf2 = (const float*)d_in[11];
  const float* Wb = (const float*)d_in[12];
  const float* A_log = (const float*)d_in[13];
  const float* dt_bias = (const float*)d_in[14];
  const float* Wg1 = (const float*)d_in[15];
  const float* Wg2 = (const float*)d_in[16];
  const float* bg2 = (const float*)d_in[17];
  const float* w_norm = (const float*)d_in[18];
  float* out = (float*)d_out;

  float* ws = (float*)d_ws;
  const size_t SZ = (size_t)S_LEN * KD_;  // 2M
  float* q_pre = ws;
  float* k_pre = ws + SZ;
  float* v_pre = ws + 2 * SZ;
  float* ve_pre = ws + 3 * SZ;
  float* q_c = ws + 4 * SZ;
  float* k_c = ws + 5 * SZ;
  float* v_mix = ws + 6 * SZ;
  float* f1 = ve_pre;                              // [S,128] after conv
  float* bpre = ve_pre + 2 * (size_t)S_LEN * DV_;  // [S,8]
  float* graw = q_pre;
  float* graw2 = k_pre;
  float* o_buf = v_pre;
  // bf16 area after 14M floats
  uint16_t* bws = (uint16_t*)(ws + 7 * SZ);
  uint16_t* xb = bws;                    // 2M
  uint16_t* veb = xb + SZ;               // 2M
  uint16_t* Wqb = veb + SZ;              // 1M
  uint16_t* Wkb = Wqb + (size_t)KD_ * DMODEL;
  uint16_t* Wvb = Wkb + (size_t)KD_ * DMODEL;
  uint16_t* Wob = Wvb + (size_t)KD_ * DMODEL;
  uint16_t* Wg1b = Wob + (size_t)DMODEL * KD_;     // 128K
  uint16_t* Wg2b = Wg1b + (size_t)DV_ * DMODEL;    // 128K
  uint16_t* g1b = Wg2b + (size_t)KD_ * DV_;        // 256K [S,128]
  uint16_t* ob = g1b + (size_t)S_LEN * DV_;        // 2M

  dim3 blk(256);
  int ew_blocks = (S_LEN * KD_ + 255) / 256;

  // ---- casts ----
  CastArgs ca;
  ca.s[0] = x;   ca.d[0] = xb;   ca.n[0] = S_LEN * DMODEL;
  ca.s[1] = ve;  ca.d[1] = veb;  ca.n[1] = S_LEN * DMODEL;
  ca.s[2] = Wq;  ca.d[2] = Wqb;  ca.n[2] = KD_ * DMODEL;
  ca.s[3] = Wk;  ca.d[3] = Wkb;  ca.n[3] = KD_ * DMODEL;
  ca.s[4] = Wv;  ca.d[4] = Wvb;  ca.n[4] = KD_ * DMODEL;
  ca.s[5] = Wo;  ca.d[5] = Wob;  ca.n[5] = DMODEL * KD_;
  ca.s[6] = Wg1; ca.d[6] = Wg1b; ca.n[6] = DV_ * DMODEL;
  ca.s[7] = Wg2; ca.d[7] = Wg2b; ca.n[7] = KD_ * DV_;
  cast_multi<<<dim3(1024, 8), blk, 0, stream>>>(ca);

  // ---- q/k/v/ve projections: 4 jobs, one launch (512 blocks) ----
  GJobs jq;
  jq.A[0] = xb;  jq.B[0] = Wqb; jq.C[0] = q_pre;
  jq.A[1] = xb;  jq.B[1] = Wkb; jq.C[1] = k_pre;
  jq.A[2] = xb;  jq.B[2] = Wvb; jq.C[2] = v_pre;
  jq.A[3] = veb; jq.B[3] = Wvb; jq.C[3] = ve_pre;
  gemm_mfma<false><<<dim3(8, 16, 4), blk, 0, stream>>>(jq, KD_, DMODEL);

  conv_silu_mix<<<ew_blocks, blk, 0, stream>>>(q_pre, k_pre, v_pre, ve_pre,
                                               wq_conv, wk_conv, wv_conv, lam,
                                               q_c, k_c, v_mix);

  // ---- g-decay path kept fp32 (error amplified by A<=16 in exp) ----
  gemm_abt<<<dim3(2, 32), blk, 0, stream>>>(x, Wf1, f1, S_LEN, DV_, DMODEL);
  gemm_abt<<<dim3(1, 32), blk, 0, stream>>>(x, Wb, bpre, S_LEN, NH, DMODEL);
  gemm_abt<<<dim3(16, 32), blk, 0, stream>>>(f1, Wf2, graw, S_LEN, KD_, DMODEL == 0 ? 0 : DV_);

  // ---- output-gate path in bf16 ----
  GJobs jg1;
  jg1.A[0] = xb; jg1.B[0] = Wg1b; jg1.C[0] = g1b;
  jg1.A[1] = xb; jg1.B[1] = Wg1b; jg1.C[1] = g1b;
  jg1.A[2] = xb; jg1.B[2] = Wg1b; jg1.C[2] = g1b;
  jg1.A[3] = xb; jg1.B[3] = Wg1b; jg1.C[3] = g1b;
  gemm_mfma<true><<<dim3(1, 16, 1), blk, 0, stream>>>(jg1, DV_, DMODEL);
  GJobs jg2;
  jg2.A[0] = g1b; jg2.B[0] = Wg2b; jg2.C[0] = graw2;
  jg2.A[1] = g1b; jg2.B[1] = Wg2b; jg2.C[1] = graw2;
  jg2.A[2] = g1b; jg2.B[2] = Wg2b; jg2.C[2] = graw2;
  jg2.A[3] = g1b; jg2.B[3] = Wg2b; jg2.C[3] = graw2;
  gemm_mfma<false><<<dim3(8, 16, 1), blk, 0, stream>>>(jg2, KD_, DV_);

  eg_beta_gate<<<ew_blocks, blk, 0, stream>>>(graw, graw2, bpre, dt_bias, A_log, bg2);
  l2norm_qk<<<dim3(S_LEN * NH), dim3(64), 0, stream>>>(q_c, k_c);
  kda_scan<<<dim3(64), blk, 0, stream>>>(q_c, k_c, v_mix, graw, bpre, o_buf);
  gated_rmsnorm<<<dim3(S_LEN * NH), dim3(64), 0, stream>>>(o_buf, graw2, w_norm, ob);

  GJobs jo;
  jo.A[0] = ob; jo.B[0] = Wob; jo.C[0] = out;
  jo.A[1] = ob; jo.B[1] = Wob; jo.C[1] = out;
  jo.A[2] = ob; jo.B[2] = Wob; jo.C[2] = out;
  jo.A[3] = ob; jo.B[3] = Wob; jo.C[3] = out;
  gemm_mfma<false><<<dim3(8, 16, 1), blk, 0, stream>>>(jo, DMODEL, KD_);
}